// Round 6
// baseline (164.296 us; speedup 1.0000x reference)
//
#include <hip/hip_runtime.h>
#include <cstdint>
#include <cstddef>

#define BB 16
#define NN 4096
#define EE 131072
#define CIN 256
#define COUT 256
#define NCH 16
#define CHE (EE / NCH)   // 8192 edges per chunk

typedef __attribute__((ext_vector_type(8))) __bf16 bf16x8;
typedef __attribute__((ext_vector_type(4))) float f32x4;
typedef __attribute__((ext_vector_type(2))) float f32x2;

#define GLDS16(g, l) __builtin_amdgcn_global_load_lds( \
    (const __attribute__((address_space(1))) uint32_t*)(g), \
    (__attribute__((address_space(3))) uint32_t*)(l), 16, 0, 0)

// ---------------- W transpose + bf16 cast: wt[n][k] = (bf16)W[k][n] ----------------
__global__ __launch_bounds__(256) void cvt_wt_kernel(const float* __restrict__ W, __bf16* __restrict__ wt) {
    int n = blockIdx.x;
    int k = threadIdx.x;
    wt[n * CIN + k] = (__bf16)W[(size_t)k * COUT + n];
}

// ---------------- phase A: hist (256 blocks) ∥ x->bf16 cvt (8192 blocks) ----------------
__global__ __launch_bounds__(256) void phaseA_kernel(const float* __restrict__ x, __bf16* __restrict__ xbf,
                                                     const int* __restrict__ ei, const float* __restrict__ ew,
                                                     int* __restrict__ chist, float* __restrict__ wdeg) {
    __shared__ int h[NN];       // 16 KB
    __shared__ float wh[NN];    // 16 KB
    int bid = blockIdx.x;
    int tid = threadIdx.x;
    if (bid < BB * NCH) {
        int b = bid >> 4, c = bid & (NCH - 1);
        for (int i = tid; i < NN; i += 256) { h[i] = 0; wh[i] = 0.f; }
        __syncthreads();
        const int* rows = ei + (size_t)b * 2 * EE + (size_t)c * CHE;
        const float* w = ew + (size_t)b * EE + (size_t)c * CHE;
        #pragma unroll 4
        for (int j = 0; j < CHE / 256; ++j) {
            int row = rows[j * 256 + tid];
            float wv = w[j * 256 + tid];
            atomicAdd(&h[row], 1);
            atomicAdd(&wh[row], wv);
        }
        __syncthreads();
        int* co = chist + ((size_t)b * NCH + c) * NN;
        float* wo = wdeg + ((size_t)b * NCH + c) * NN;
        for (int i = tid; i < NN; i += 256) { co[i] = h[i]; wo[i] = wh[i]; }
    } else {
        size_t u = (size_t)(bid - BB * NCH) * 256 + tid;  // 8-elem unit, 2,097,152 total
        const float* g = &x[u * 8];
        float4 f0 = *reinterpret_cast<const float4*>(g);
        float4 f1 = *reinterpret_cast<const float4*>(g + 4);
        bf16x8 v;
        v[0] = (__bf16)f0.x; v[1] = (__bf16)f0.y; v[2] = (__bf16)f0.z; v[3] = (__bf16)f0.w;
        v[4] = (__bf16)f1.x; v[5] = (__bf16)f1.y; v[6] = (__bf16)f1.z; v[7] = (__bf16)f1.w;
        *reinterpret_cast<bf16x8*>(&xbf[u * 8]) = v;
    }
}

// ---------------- per-batch scan (shfl-based): row offsets + per-chunk bases + dinv ----------------
__global__ __launch_bounds__(1024) void scan2_kernel(const int* __restrict__ chist, const float* __restrict__ wdeg,
                                                     int* __restrict__ chunkbase, float* __restrict__ dinv) {
    int b = blockIdx.x, tid = threadIdx.x;
    int wid = tid >> 6, lane = tid & 63;
    __shared__ int wsum[16];
    __shared__ int wbase[16];
    __shared__ int gtot_s;
    int run[4];
    int carry = 0;
    for (int g = 0; g < 4; ++g) {
        int r = g * 1024 + tid;
        int tot = 0;
        float dsum = 1.0f;   // +1 self loop, always > 0
        #pragma unroll
        for (int c = 0; c < NCH; ++c) {
            size_t idx = ((size_t)b * NCH + c) * NN + r;
            tot += chist[idx];
            dsum += wdeg[idx];
        }
        dinv[b * NN + r] = rsqrtf(dsum);
        int incl = tot;
        #pragma unroll
        for (int off = 1; off < 64; off <<= 1) {
            int t = __shfl_up(incl, off, 64);
            if (lane >= off) incl += t;
        }
        if (lane == 63) wsum[wid] = incl;
        __syncthreads();
        if (wid == 0) {
            int v = (lane < 16) ? wsum[lane] : 0;
            int winc = v;
            #pragma unroll
            for (int off = 1; off < 16; off <<= 1) {
                int t = __shfl_up(winc, off, 64);
                if (lane >= off) winc += t;
            }
            if (lane < 16) wbase[lane] = winc - v;
            if (lane == 15) gtot_s = winc;
        }
        __syncthreads();
        run[g] = carry + wbase[wid] + (incl - tot);
        carry += gtot_s;
    }
    for (int g = 0; g < 4; ++g) {
        int acc = run[g];
        int r = g * 1024 + tid;
        #pragma unroll
        for (int c = 0; c < NCH; ++c) {
            size_t idx = ((size_t)b * NCH + c) * NN + r;
            int t = chist[idx];
            chunkbase[idx] = acc;   // chunkbase[c=0][r] == CSR row offset
            acc += t;
        }
    }
}

// ---------------- scatter into CSR slots — LDS atomics only, XCD-pinned ----------------
__global__ __launch_bounds__(256) void scatter2_kernel(const int* __restrict__ ei, const float* __restrict__ ew,
                                                       const float* __restrict__ dinv, const int* __restrict__ chunkbase,
                                                       int2* __restrict__ csr) {
    __shared__ int basebuf[NN];     // 16 KB
    __shared__ float dinvs[NN];     // 16 KB
    int bid = blockIdx.x;           // 256 blocks
    int xcd = bid & 7;
    int j = bid >> 3;
    int b = xcd * 2 + (j >> 4);
    int c = j & (NCH - 1);
    int tid = threadIdx.x;
    for (int i = tid; i < NN; i += 256) {
        basebuf[i] = chunkbase[((size_t)b * NCH + c) * NN + i];
        dinvs[i] = dinv[b * NN + i];
    }
    __syncthreads();
    const int* rows = ei + (size_t)b * 2 * EE + (size_t)c * CHE;
    const int* cols = rows + EE;
    const float* w = ew + (size_t)b * EE + (size_t)c * CHE;
    int2* cs = csr + (size_t)b * EE;
    #pragma unroll 4
    for (int jj = 0; jj < CHE / 256; ++jj) {
        int e = jj * 256 + tid;
        int row = rows[e];
        int col = cols[e];
        float nm = dinvs[row] * w[e] * dinvs[col];
        int pos = atomicAdd(&basebuf[row], 1);
        int2 pk; pk.x = col * (COUT * 2); pk.y = __float_as_int(nm);
        cs[pos] = pk;
    }
}

// ---------------- MFMA GEMM via global_load_lds: xw(bf16) = xbf @ wt^T ----------------
__global__ __launch_bounds__(256) void gemm_glds_kernel(const __bf16* __restrict__ xbf, const __bf16* __restrict__ wt,
                                                        __bf16* __restrict__ xw) {
    __shared__ __bf16 As[128 * 64];   // 16 KB, layout [r][k], r=M-rows
    __shared__ __bf16 Bs[128 * 64];   // 16 KB, layout [c][k], c=N-cols
    int tid = threadIdx.x;
    int lane = tid & 63;
    int wave = tid >> 6;
    int bx = blockIdx.x >> 1, by = blockIdx.x & 1;   // 1024 blocks -> (512, 2)
    int row0 = bx * 128, col0 = by * 128;
    int wr = wave >> 1, wc = wave & 1;
    int hi = lane >> 4, lo = lane & 15;
    int lr = lane >> 3, lk = (lane & 7) * 8;         // staging: lane -> (row-sub, k-off)
    f32x4 acc[4][4] = {};

    for (int kk = 0; kk < CIN; kk += 64) {
        #pragma unroll
        for (int j = 0; j < 4; ++j) {
            int seg = j * 4 + wave;                  // 16 segments of 8 rows
            const __bf16* ga = &xbf[(size_t)(row0 + seg * 8 + lr) * CIN + kk + lk];
            const __bf16* gb = &wt [(size_t)(col0 + seg * 8 + lr) * CIN + kk + lk];
            GLDS16(ga, &As[seg * 512]);              // wave-uniform LDS base + lane*16B
            GLDS16(gb, &Bs[seg * 512]);
        }
        __syncthreads();
        #pragma unroll
        for (int ks = 0; ks < 2; ++ks) {
            bf16x8 a[4], b[4];
            #pragma unroll
            for (int m = 0; m < 4; ++m)
                a[m] = *reinterpret_cast<const bf16x8*>(&As[(wr * 64 + m * 16 + lo) * 64 + ks * 32 + 8 * hi]);
            #pragma unroll
            for (int n = 0; n < 4; ++n)
                b[n] = *reinterpret_cast<const bf16x8*>(&Bs[(wc * 64 + n * 16 + lo) * 64 + ks * 32 + 8 * hi]);
            #pragma unroll
            for (int m = 0; m < 4; ++m)
                #pragma unroll
                for (int n = 0; n < 4; ++n)
                    acc[m][n] = __builtin_amdgcn_mfma_f32_16x16x32_bf16(a[m], b[n], acc[m][n], 0, 0, 0);
        }
        __syncthreads();
    }
    #pragma unroll
    for (int m = 0; m < 4; ++m)
        #pragma unroll
        for (int n = 0; n < 4; ++n)
            #pragma unroll
            for (int r = 0; r < 4; ++r) {
                int row = row0 + wr * 64 + m * 16 + hi * 4 + r;
                int col = col0 + wc * 64 + n * 16 + lo;
                xw[(size_t)row * COUT + col] = (__bf16)acc[m][n][r];
            }
}

// ---------------- CSR aggregation: scalar CSR reads, 16-deep MLP, tiered tail ----------------
__global__ __launch_bounds__(256) void aggregate_kernel(const __bf16* __restrict__ xw, const float* __restrict__ dinv,
                                                        const int* __restrict__ chunkbase, const int2* __restrict__ csr,
                                                        float* __restrict__ out) {
    int bid = blockIdx.x;            // 16384 blocks
    int xcd = bid & 7;
    int idx = bid >> 3;
    int b = xcd * 2 + (idx >> 10);
    int rowblk = idx & 1023;
    int wave = threadIdx.x >> 6;
    int lane = threadIdx.x & 63;
    int n = rowblk * 4 + wave;

    const int* cb = chunkbase + (size_t)b * NCH * NN;
    int s = __builtin_amdgcn_readfirstlane(cb[n]);
    int eRaw = (n == NN - 1) ? EE : cb[n + 1];
    int e = __builtin_amdgcn_readfirstlane(eRaw);
    int cnt = e - s;
    const int2* cs = csr + (size_t)b * EE + s;

    const char* xwb = (const char*)(xw + (size_t)b * NN * COUT) + lane * 8;
    float di = dinv[b * NN + n];
    float sn = di * di;
    uint2 sraw = *reinterpret_cast<const uint2*>(xwb + n * (COUT * 2));
    f32x2 acc01, acc23;
    acc01.x = sn * __uint_as_float(sraw.x << 16);
    acc01.y = sn * __uint_as_float(sraw.x & 0xffff0000u);
    acc23.x = sn * __uint_as_float(sraw.y << 16);
    acc23.y = sn * __uint_as_float(sraw.y & 0xffff0000u);

    int i = 0;
    for (; i + 16 <= cnt; i += 16) {
        int2 q[16];
        #pragma unroll
        for (int u = 0; u < 16; ++u) q[u] = cs[i + u];   // wave-uniform -> scalar loads
        uint2 raw[16];
        #pragma unroll
        for (int u = 0; u < 16; ++u) raw[u] = *reinterpret_cast<const uint2*>(xwb + q[u].x);
        #pragma unroll
        for (int u = 0; u < 16; ++u) {
            float nm = __int_as_float(q[u].y);
            f32x2 v01, v23;
            v01.x = __uint_as_float(raw[u].x << 16);
            v01.y = __uint_as_float(raw[u].x & 0xffff0000u);
            v23.x = __uint_as_float(raw[u].y << 16);
            v23.y = __uint_as_float(raw[u].y & 0xffff0000u);
            acc01 += nm * v01;
            acc23 += nm * v23;
        }
    }
    if (i + 8 <= cnt) {
        int2 q[8];
        #pragma unroll
        for (int u = 0; u < 8; ++u) q[u] = cs[i + u];
        uint2 raw[8];
        #pragma unroll
        for (int u = 0; u < 8; ++u) raw[u] = *reinterpret_cast<const uint2*>(xwb + q[u].x);
        #pragma unroll
        for (int u = 0; u < 8; ++u) {
            float nm = __int_as_float(q[u].y);
            f32x2 v01, v23;
            v01.x = __uint_as_float(raw[u].x << 16);
            v01.y = __uint_as_float(raw[u].x & 0xffff0000u);
            v23.x = __uint_as_float(raw[u].y << 16);
            v23.y = __uint_as_float(raw[u].y & 0xffff0000u);
            acc01 += nm * v01;
            acc23 += nm * v23;
        }
        i += 8;
    }
    if (i < cnt) {   // clamped tail (<8 real edges; padding uses norm=0)
        int2 q[8];
        float nmv[8];
        #pragma unroll
        for (int u = 0; u < 8; ++u) {
            int j = i + u;
            q[u] = cs[(j < cnt) ? j : (cnt - 1)];
            nmv[u] = (j < cnt) ? __int_as_float(q[u].y) : 0.0f;
        }
        uint2 raw[8];
        #pragma unroll
        for (int u = 0; u < 8; ++u) raw[u] = *reinterpret_cast<const uint2*>(xwb + q[u].x);
        #pragma unroll
        for (int u = 0; u < 8; ++u) {
            float nm = nmv[u];
            f32x2 v01, v23;
            v01.x = __uint_as_float(raw[u].x << 16);
            v01.y = __uint_as_float(raw[u].x & 0xffff0000u);
            v23.x = __uint_as_float(raw[u].y << 16);
            v23.y = __uint_as_float(raw[u].y & 0xffff0000u);
            acc01 += nm * v01;
            acc23 += nm * v23;
        }
    }
    float4 o = make_float4(fmaxf(acc01.x, 0.f), fmaxf(acc01.y, 0.f), fmaxf(acc23.x, 0.f), fmaxf(acc23.y, 0.f));
    *reinterpret_cast<float4*>(&out[((size_t)b * NN + n) * COUT + 4 * lane]) = o;
}

// ---------------- fallback (atomic) path ----------------
__global__ __launch_bounds__(256) void init_deg_kernel(float* __restrict__ deg, float v) {
    int i = blockIdx.x * 256 + threadIdx.x;
    if (i < BB * NN) deg[i] = v;
}

__global__ __launch_bounds__(256) void deg_only_kernel(const int* __restrict__ ei, const float* __restrict__ ew,
                                                       float* __restrict__ deg) {
    int idx = blockIdx.x * 256 + threadIdx.x;
    if (idx >= BB * EE) return;
    int b = idx / EE, e = idx - b * EE;
    atomicAdd(&deg[b * NN + ei[(size_t)b * 2 * EE + e]], ew[(size_t)b * EE + e]);
}

__global__ __launch_bounds__(256) void deginv_kernel(const float* __restrict__ deg, float* __restrict__ dinv) {
    int i = blockIdx.x * 256 + threadIdx.x;
    if (i < BB * NN) {
        float d = deg[i];
        dinv[i] = (d > 0.0f) ? rsqrtf(d) : 0.0f;
    }
}

__global__ __launch_bounds__(256) void gemm_f32src_kernel(const float* __restrict__ x, const __bf16* __restrict__ wt,
                                                          __bf16* __restrict__ xw) {
    __shared__ __bf16 As[128][64];
    __shared__ __bf16 Bs[128][64];
    int tid = threadIdx.x;
    int lane = tid & 63;
    int wave = tid >> 6;
    int row0 = blockIdx.x * 128;
    int col0 = blockIdx.y * 128;
    int wr = wave >> 1, wc = wave & 1;
    int hi = lane >> 4, lo = lane & 15;
    f32x4 acc[4][4] = {};
    for (int kk = 0; kk < CIN; kk += 64) {
        #pragma unroll
        for (int j = 0; j < 4; ++j) {
            int c = j * 256 + tid;
            int r = c >> 3, kq = c & 7;
            const float* g = &x[(size_t)(row0 + r) * CIN + kk + 8 * kq];
            float4 f0 = *reinterpret_cast<const float4*>(g);
            float4 f1 = *reinterpret_cast<const float4*>(g + 4);
            bf16x8 v;
            v[0] = (__bf16)f0.x; v[1] = (__bf16)f0.y; v[2] = (__bf16)f0.z; v[3] = (__bf16)f0.w;
            v[4] = (__bf16)f1.x; v[5] = (__bf16)f1.y; v[6] = (__bf16)f1.z; v[7] = (__bf16)f1.w;
            *reinterpret_cast<bf16x8*>(&As[r][8 * kq]) = v;
        }
        #pragma unroll
        for (int j = 0; j < 4; ++j) {
            int c = j * 256 + tid;
            int r = c >> 3, kq = c & 7;
            *reinterpret_cast<bf16x8*>(&Bs[r][8 * kq]) =
                *reinterpret_cast<const bf16x8*>(&wt[(size_t)(col0 + r) * CIN + kk + 8 * kq]);
        }
        __syncthreads();
        #pragma unroll
        for (int ks = 0; ks < 2; ++ks) {
            bf16x8 a[4], b[4];
            #pragma unroll
            for (int m = 0; m < 4; ++m)
                a[m] = *reinterpret_cast<const bf16x8*>(&As[wr * 64 + m * 16 + lo][ks * 32 + 8 * hi]);
            #pragma unroll
            for (int n = 0; n < 4; ++n)
                b[n] = *reinterpret_cast<const bf16x8*>(&Bs[wc * 64 + n * 16 + lo][ks * 32 + 8 * hi]);
            #pragma unroll
            for (int m = 0; m < 4; ++m)
                #pragma unroll
                for (int n = 0; n < 4; ++n)
                    acc[m][n] = __builtin_amdgcn_mfma_f32_16x16x32_bf16(a[m], b[n], acc[m][n], 0, 0, 0);
        }
        __syncthreads();
    }
    #pragma unroll
    for (int m = 0; m < 4; ++m)
        #pragma unroll
        for (int n = 0; n < 4; ++n)
            #pragma unroll
            for (int r = 0; r < 4; ++r) {
                int row = row0 + wr * 64 + m * 16 + hi * 4 + r;
                int col = col0 + wc * 64 + n * 16 + lo;
                xw[(size_t)row * COUT + col] = (__bf16)acc[m][n][r];
            }
}

__global__ __launch_bounds__(256) void self_kernel(const __bf16* __restrict__ xw, const float* __restrict__ dinv,
                                                   float* __restrict__ out) {
    int bn = blockIdx.x;
    int c = threadIdx.x;
    float di = dinv[bn];
    out[(size_t)bn * COUT + c] = di * di * (float)xw[(size_t)bn * COUT + c];
}

__global__ __launch_bounds__(256) void scatter_atomic_kernel(const int* __restrict__ ei, const float* __restrict__ ew,
                                                             const float* __restrict__ dinv,
                                                             const __bf16* __restrict__ xw, float* __restrict__ out) {
    int be = blockIdx.x;
    int b = be / EE, e = be - b * EE;
    int c = threadIdx.x;
    int row = ei[(size_t)b * 2 * EE + e];
    int col = ei[(size_t)b * 2 * EE + EE + e];
    float w = ew[(size_t)b * EE + e];
    float nm = dinv[b * NN + row] * w * dinv[b * NN + col];
    const __bf16* xwb = xw + (size_t)b * NN * COUT;
    atomicAdd(&out[((size_t)b * NN + row) * COUT + c], nm * (float)xwb[(size_t)col * COUT + c]);
}

__global__ __launch_bounds__(256) void relu_kernel(float* __restrict__ out) {
    size_t i = (size_t)blockIdx.x * 256 + threadIdx.x;
    out[i] = fmaxf(out[i], 0.0f);
}

extern "C" void kernel_launch(void* const* d_in, const int* in_sizes, int n_in,
                              void* d_out, int out_size, void* d_ws, size_t ws_size,
                              hipStream_t stream) {
    const float* x  = (const float*)d_in[0];
    const int*   ei = (const int*)d_in[1];
    const float* ew = (const float*)d_in[2];
    const float* Wm = (const float*)d_in[3];
    float* out = (float*)d_out;

    char* ws = (char*)d_ws;
    size_t off = 0;
    auto alloc = [&](size_t bytes) -> void* {
        void* p = ws + off;
        off += (bytes + 255) & ~(size_t)255;
        return p;
    };
    __bf16* xw        = (__bf16*)alloc((size_t)BB * NN * COUT * 2);   // 32 MB
    __bf16* xbf       = (__bf16*)alloc((size_t)BB * NN * CIN * 2);    // 32 MB
    int*    chist     = (int*)alloc((size_t)BB * NCH * NN * 4);       // 4 MB
    float*  wdeg      = (float*)alloc((size_t)BB * NCH * NN * 4);     // 4 MB
    int*    chunkbase = (int*)alloc((size_t)BB * NCH * NN * 4);       // 4 MB
    float*  dinv      = (float*)alloc((size_t)BB * NN * 4);
    __bf16* wt        = (__bf16*)alloc((size_t)CIN * COUT * 2);
    int2*   csr       = (int2*)xbf;   // 16 MB alias; xbf dead after gemm, csr written after
    float*  deg_fb    = (float*)chist; // fallback-only alias
    bool use_csr = (ws_size >= off);

    cvt_wt_kernel<<<COUT, CIN, 0, stream>>>(Wm, wt);

    if (use_csr) {
        phaseA_kernel<<<BB * NCH + (BB * NN * CIN) / (256 * 8), 256, 0, stream>>>(x, xbf, ei, ew, chist, wdeg);
        scan2_kernel<<<BB, 1024, 0, stream>>>(chist, wdeg, chunkbase, dinv);
        gemm_glds_kernel<<<(BB * NN / 128) * (COUT / 128), 256, 0, stream>>>(xbf, wt, xw);
        scatter2_kernel<<<BB * NCH, 256, 0, stream>>>(ei, ew, dinv, chunkbase, csr);
        aggregate_kernel<<<BB * NN / 4, 256, 0, stream>>>(xw, dinv, chunkbase, csr, out);
    } else {
        const int bnBlocks = (BB * NN) / 256;
        init_deg_kernel<<<bnBlocks, 256, 0, stream>>>(deg_fb, 1.0f);
        deg_only_kernel<<<(BB * EE) / 256, 256, 0, stream>>>(ei, ew, deg_fb);
        deginv_kernel<<<bnBlocks, 256, 0, stream>>>(deg_fb, dinv);
        dim3 ggrid((BB * NN) / 128, COUT / 128);
        gemm_f32src_kernel<<<ggrid, 256, 0, stream>>>(x, wt, xw);
        self_kernel<<<BB * NN, 256, 0, stream>>>(xw, dinv, out);
        scatter_atomic_kernel<<<BB * EE, 256, 0, stream>>>(ei, ew, dinv, xw, out);
        relu_kernel<<<(BB * NN * COUT) / 256, 256, 0, stream>>>(out);
    }
}